// Round 25
// baseline (92.619 us; speedup 1.0000x reference)
//
#include <hip/hip_runtime.h>
#include <hip/hip_bf16.h>

#define BATCH 256
#define L 1024
#define C 16
#define POOL 512
#define PCOLS 5632
#define FDIM 90112        // 11 levels * 8192
#define H1 128
#define H2 64

#define KS 256            // split-K factor for fc1 mfma GEMM
#define KCHUNK (FDIM / KS)   // 352

#define SROW 24                    // bf16 per state row (48B, 16B-aligned)
#define SBUF (1025 * SROW)         // +1 zero row
#define TREE_LDS_BYTES (2 * SBUF * 2)   // 98400 B

#define TROW 520                   // transpose-stage LDS row stride (shorts)

typedef float f32x4 __attribute__((ext_vector_type(4)));
typedef short bf16x8 __attribute__((ext_vector_type(8)));
typedef unsigned long long u64;

__device__ __forceinline__ unsigned short f2b(float f) {
    union { __hip_bfloat16 h; unsigned short u; } cv;
    cv.h = __float2bfloat16(f);          // RNE, hardware v_cvt
    return cv.u;
}
__device__ __forceinline__ unsigned int pk(float lo, float hi) {
    return (unsigned int)f2b(lo) | ((unsigned int)f2b(hi) << 16);
}

// ---------------- Kernel 1: tree via MFMA + fused w1 convert/permute ----------------
// pooled layout: f_new = level*8192 + pos2*16 + c   (w1 permuted to match)
// Per level: PHASE 1 issues all 8 ds_read_b128 (4 tiles) into registers so the
// LDS pipe streams; PHASE 2 runs the 4 MFMA+epilogue chains.
__launch_bounds__(1024, 4)
__global__ void tree_kernel(const float* __restrict__ x,
                            const float* __restrict__ leaf_w,
                            const float* __restrict__ leaf_b,
                            const float* __restrict__ conv_w,
                            const float* __restrict__ conv_b,
                            const float* __restrict__ bn_gamma,
                            const float* __restrict__ bn_beta,
                            const float* __restrict__ node_w,
                            unsigned short* __restrict__ pooledb,
                            const float* __restrict__ w1,
                            unsigned short* __restrict__ w1p) {
    extern __shared__ short smem[];
    short* buf0 = smem;
    short* buf1 = smem + SBUF;

    const int b   = blockIdx.x;
    const int tid = threadIdx.x;
    const int lane = tid & 63;
    const int wv   = tid >> 6;
    const int n    = lane & 15;
    const int g    = lane >> 4;

    if (tid < SROW) {
        buf0[1024 * SROW + tid] = 0;
        buf1[1024 * SROW + tid] = 0;
    }

    bf16x8 A1, A2;
#pragma unroll
    for (int j = 0; j < 8; ++j) {
        const int ci = (g & 1) * 8 + j;
        A1[j] = (short)f2b(conv_w[(n * C + ci) * 3 + (g >> 1)]);
        A2[j] = (g < 2) ? (short)f2b(conv_w[(n * C + ci) * 3 + 2]) : (short)0;
    }
    float sc4[4], bt4[4];
#pragma unroll
    for (int r = 0; r < 4; ++r) {
        const int co = g * 4 + r;
        float s = bn_gamma[co] / sqrtf(1.0f + 1e-5f);
        sc4[r] = s;
        bt4[r] = conv_b[co] * s + bn_beta[co];
    }

    // ---- leaf stage: 1 position per thread ----
    {
        const float xv = x[b * L + tid];
        const float nw = node_w[tid];
        const float4* lwa = (const float4*)(leaf_w + 16 * tid);
        const float4* lba = (const float4*)(leaf_b + 16 * tid);
        short* row = buf0 + tid * SROW;
#pragma unroll 1
        for (int q = 0; q < 4; ++q) {
            float4 wq = lwa[q], bq = lba[q];
            float v0 = (xv * wq.x + bq.x) * nw;
            float v1 = (xv * wq.y + bq.y) * nw;
            float v2 = (xv * wq.z + bq.z) * nw;
            float v3 = (xv * wq.w + bq.w) * nw;
            *(u64*)(row + 4 * q) =
                (u64)pk(v0, v1) | ((u64)pk(v2, v3) << 32);
            float p0 = fmaxf(v0, __shfl_xor(v0, 1));
            float p1 = fmaxf(v1, __shfl_xor(v1, 1));
            float p2 = fmaxf(v2, __shfl_xor(v2, 1));
            float p3 = fmaxf(v3, __shfl_xor(v3, 1));
            if (!(tid & 1)) {
                *(u64*)(pooledb + (long)b * FDIM + (tid >> 1) * 16 + 4 * q) =
                    (u64)pk(p0, p1) | ((u64)pk(p2, p3) << 32);
            }
        }
        __syncthreads();   // zero rows + leaf state visible to all waves
    }

    // ---- 10 levels via MFMA ----
    short* bin  = buf0;
    short* bout = buf1;
    int noff = L;
    for (int d = 0; d < 10; ++d) {
        const int sh = d + 1;
        const int mask = (1 << sh) - 1;

        // PHASE 1: issue all tap reads (8x ds_read_b128) -> registers
        bf16x8 B1s[4], B2s[4];
#pragma unroll
        for (int ti = 0; ti < 4; ++ti) {
            const int pos = (wv * 4 + ti) * 16 + n;
            const bool ok1 = (g >= 2) || ((pos & mask) != 0);
            const int r1 = ok1 ? (pos + (g >> 1) - 1) : 1024;
            B1s[ti] = *(const bf16x8*)(bin + r1 * SROW + (g & 1) * 8);
            const bool ok2 = ((pos & mask) != mask);
            const int r2 = ok2 ? (pos + 1) : 1024;
            B2s[ti] = *(const bf16x8*)(bin + r2 * SROW + (g & 1) * 8);
        }

        // PHASE 2: MFMA + epilogue per tile
#pragma unroll
        for (int ti = 0; ti < 4; ++ti) {
            const int pos = (wv * 4 + ti) * 16 + n;

            f32x4 acc = {0.f, 0.f, 0.f, 0.f};
            acc = __builtin_amdgcn_mfma_f32_16x16x32_bf16(A1, B1s[ti], acc, 0, 0, 0);
            acc = __builtin_amdgcn_mfma_f32_16x16x32_bf16(A2, B2s[ti], acc, 0, 0, 0);

            const float nwv = node_w[noff + (pos >> sh)];
            float z[4];
#pragma unroll
            for (int r = 0; r < 4; ++r)
                z[r] = fmaxf(fmaf(sc4[r], acc[r], bt4[r]), 0.f) * nwv;

            if (d < 9) {
                *(u64*)(bout + pos * SROW + g * 4) =
                    (u64)pk(z[0], z[1]) | ((u64)pk(z[2], z[3]) << 32);
            }

            float pz0 = fmaxf(z[0], __shfl_xor(z[0], 1));
            float pz1 = fmaxf(z[1], __shfl_xor(z[1], 1));
            float pz2 = fmaxf(z[2], __shfl_xor(z[2], 1));
            float pz3 = fmaxf(z[3], __shfl_xor(z[3], 1));
            if (!(n & 1)) {
                *(u64*)(pooledb + (long)b * FDIM + sh * 8192 + (pos >> 1) * 16 + g * 4) =
                    (u64)pk(pz0, pz1) | ((u64)pk(pz2, pz3) << 32);
            }
        }

        if (d >= 5 && d < 9) {
            __syncthreads();                 // next level reads cross-wave
        } else {
            asm volatile("s_waitcnt lgkmcnt(0)" ::: "memory");
        }

        short* t = bin; bin = bout; bout = t;
        noff += (512 >> d);
    }

    __syncthreads();   // protect smem reuse below

    // ---- tail: w1 f32 -> bf16 with feature permutation (grid-stride units) ----
    unsigned short* st = (unsigned short*)smem;   // [16][TROW] staging
    for (int unit = b; unit < 11 * H1; unit += BATCH) {
        const int lev = unit >> 7;
        const int nr  = unit & 127;
        const float* src = w1 + (long)nr * FDIM + lev * POOL;
#pragma unroll 2
        for (int i = tid; i < 2048; i += 1024) {       // i = c*128 + q (float4)
            const int c = i >> 7, q = i & 127;
            float4 v = *(const float4*)(src + (long)c * PCOLS + 4 * q);
            *(u64*)(st + c * TROW + 4 * q) =
                (u64)pk(v.x, v.y) | ((u64)pk(v.z, v.w) << 32);
        }
        __syncthreads();
#pragma unroll 2
        for (int i = tid; i < 2048; i += 1024) {       // i = pos2*4 + c4 (u64)
            const int pos2 = i >> 2, c4 = i & 3;
            unsigned short s0 = st[(c4 * 4 + 0) * TROW + pos2];
            unsigned short s1 = st[(c4 * 4 + 1) * TROW + pos2];
            unsigned short s2 = st[(c4 * 4 + 2) * TROW + pos2];
            unsigned short s3 = st[(c4 * 4 + 3) * TROW + pos2];
            *(u64*)(w1p + (long)nr * FDIM + lev * 8192 + pos2 * 16 + c4 * 4) =
                (u64)s0 | ((u64)s1 << 16) | ((u64)s2 << 32) | ((u64)s3 << 48);
        }
        __syncthreads();
    }
}

// ---------------- Kernel 2: fc1 via MFMA, M=256/block for B-reuse ----------------
// partial layout now [row][ks][col] so fc_tail streams contiguously.
__launch_bounds__(512, 2)
__global__ void fc1_mfma(const unsigned short* __restrict__ pooledb,
                         const unsigned short* __restrict__ w1b,
                         float* __restrict__ partial) {
    const int bid = blockIdx.x;
    const int ks  = bid & (KS - 1);      // 0..255
    const int bn  = bid >> 8;            // 0..1

    const int tid  = threadIdx.x;
    const int wv   = tid >> 6;           // 0..7
    const int lane = tid & 63;
    const int lrow = lane & 15;
    const int lk   = (lane >> 4) * 8;

    const int m0 = wv * 32;
    const int n0 = bn * 64;
    const int kb = ks * KCHUNK;

    const unsigned short* ap0 = pooledb + (long)(m0 + lrow) * FDIM + kb + lk;
    const unsigned short* ap1 = ap0 + (long)16 * FDIM;
    const unsigned short* bp  = w1b + (long)(n0 + lrow) * FDIM + kb + lk;

    f32x4 acc00 = {0,0,0,0}, acc01 = {0,0,0,0}, acc02 = {0,0,0,0}, acc03 = {0,0,0,0};
    f32x4 acc10 = {0,0,0,0}, acc11 = {0,0,0,0}, acc12 = {0,0,0,0}, acc13 = {0,0,0,0};

#pragma unroll 2
    for (int kk = 0; kk < KCHUNK; kk += 32) {
        bf16x8 a0 = *(const bf16x8*)(ap0 + kk);
        bf16x8 a1 = *(const bf16x8*)(ap1 + kk);
        bf16x8 b0 = *(const bf16x8*)(bp + kk);
        bf16x8 b1 = *(const bf16x8*)(bp + (long)16 * FDIM + kk);
        bf16x8 b2 = *(const bf16x8*)(bp + (long)32 * FDIM + kk);
        bf16x8 b3 = *(const bf16x8*)(bp + (long)48 * FDIM + kk);
        acc00 = __builtin_amdgcn_mfma_f32_16x16x32_bf16(a0, b0, acc00, 0, 0, 0);
        acc01 = __builtin_amdgcn_mfma_f32_16x16x32_bf16(a0, b1, acc01, 0, 0, 0);
        acc02 = __builtin_amdgcn_mfma_f32_16x16x32_bf16(a0, b2, acc02, 0, 0, 0);
        acc03 = __builtin_amdgcn_mfma_f32_16x16x32_bf16(a0, b3, acc03, 0, 0, 0);
        acc10 = __builtin_amdgcn_mfma_f32_16x16x32_bf16(a1, b0, acc10, 0, 0, 0);
        acc11 = __builtin_amdgcn_mfma_f32_16x16x32_bf16(a1, b1, acc11, 0, 0, 0);
        acc12 = __builtin_amdgcn_mfma_f32_16x16x32_bf16(a1, b2, acc12, 0, 0, 0);
        acc13 = __builtin_amdgcn_mfma_f32_16x16x32_bf16(a1, b3, acc13, 0, 0, 0);
    }

    const int rbase = (lane >> 4) * 4;
    const int ccol  = n0 + (lane & 15);
#pragma unroll
    for (int r = 0; r < 4; ++r) {
        const int row0 = m0 + rbase + r;
        float* p0 = partial + (long)row0 * (KS * H1) + ks * H1 + ccol;
        p0[0]  = acc00[r];
        p0[16] = acc01[r];
        p0[32] = acc02[r];
        p0[48] = acc03[r];
        float* p1 = p0 + (long)16 * (KS * H1);
        p1[0]  = acc10[r];
        p1[16] = acc11[r];
        p1[32] = acc12[r];
        p1[48] = acc13[r];
    }
}

// ---------------- Kernel 3: parallel partial-reduce + fc1 bias/relu + fc2 + fc3 --
// partial[b][ks][col]: block b streams its contiguous 128KB slice.
__launch_bounds__(1024)
__global__ void fc_tail(const float* __restrict__ partial,
                        const float* __restrict__ fc1_b,
                        const float* __restrict__ w2,
                        const float* __restrict__ b2,
                        const float* __restrict__ w3,
                        const float* __restrict__ b3,
                        float* __restrict__ out, int nkt) {
    __shared__ float red[8][H1];
    __shared__ float h1_s[H1];
    __shared__ float w2_s[H2 * 129];

    const int b = blockIdx.x;
    const int tid = threadIdx.x;
    const int t = tid & 127;      // h1 index
    const int q = tid >> 7;       // kt group 0..7

    const int per = nkt >> 3;     // 32
    float s = 0.f;
    const float* pb = partial + (long)b * (KS * H1) + (q * per) * H1 + t;
#pragma unroll 8
    for (int kt = 0; kt < per; ++kt)
        s += pb[kt * H1];
    red[q][t] = s;

    for (int i = tid; i < H2 * H1; i += 1024) {
        int j = i >> 7, k = i & 127;
        w2_s[j * 129 + k] = w2[i];
    }
    __syncthreads();

    if (tid < 128) {
        float ss = red[0][t] + red[1][t] + red[2][t] + red[3][t]
                 + red[4][t] + red[5][t] + red[6][t] + red[7][t];
        h1_s[t] = fmaxf(ss + fc1_b[t], 0.f);
    }
    __syncthreads();

    if (tid < 64) {
        float a2 = 0.f;
#pragma unroll 8
        for (int k = 0; k < H1; ++k) a2 = fmaf(h1_s[k], w2_s[tid * 129 + k], a2);
        float h2 = fmaxf(a2 + b2[tid], 0.f);
        float r = h2 * w3[tid];
#pragma unroll
        for (int off = 32; off > 0; off >>= 1) r += __shfl_down(r, off);
        if (tid == 0) out[b] = r + b3[0];
    }
}

extern "C" void kernel_launch(void* const* d_in, const int* in_sizes, int n_in,
                              void* d_out, int out_size, void* d_ws, size_t ws_size,
                              hipStream_t stream) {
    const float* x        = (const float*)d_in[0];
    const float* leaf_w   = (const float*)d_in[1];
    const float* leaf_b   = (const float*)d_in[2];
    const float* conv_w   = (const float*)d_in[3];
    const float* conv_b   = (const float*)d_in[4];
    const float* bn_gamma = (const float*)d_in[5];
    const float* bn_beta  = (const float*)d_in[6];
    const float* node_w   = (const float*)d_in[7];
    const float* fc1_w    = (const float*)d_in[8];
    const float* fc1_b    = (const float*)d_in[9];
    const float* fc2_w    = (const float*)d_in[10];
    const float* fc2_b    = (const float*)d_in[11];
    const float* fc3_w    = (const float*)d_in[12];
    const float* fc3_b    = (const float*)d_in[13];

    // ws: pooled bf16 (46.1MB) | w1p bf16 (23.1MB) | partial f32 (33.6MB) = 102.8MB
    unsigned short* pooledb = (unsigned short*)d_ws;
    unsigned short* w1p     = pooledb + (long)BATCH * FDIM;
    float*          partial = (float*)(w1p + (long)H1 * FDIM);

    (void)hipFuncSetAttribute((const void*)tree_kernel,
                        hipFuncAttributeMaxDynamicSharedMemorySize, TREE_LDS_BYTES);

    tree_kernel<<<BATCH, 1024, TREE_LDS_BYTES, stream>>>(
        x, leaf_w, leaf_b, conv_w, conv_b, bn_gamma, bn_beta, node_w, pooledb,
        fc1_w, w1p);

    fc1_mfma<<<2 * KS, 512, 0, stream>>>(pooledb, w1p, partial);

    fc_tail<<<BATCH, 1024, 0, stream>>>(partial, fc1_b, fc2_w, fc2_b, fc3_w, fc3_b,
                                        (float*)d_out, KS);
}

// Round 26
// 89.043 us; speedup vs baseline: 1.0402x; 1.0402x over previous
//
#include <hip/hip_runtime.h>
#include <hip/hip_bf16.h>

#define BATCH 256
#define L 1024
#define C 16
#define POOL 512
#define PCOLS 5632
#define FDIM 90112        // 11 levels * 8192
#define H1 128
#define H2 64

#define KS 256            // split-K factor for fc1 mfma GEMM
#define KCHUNK (FDIM / KS)   // 352

#define SROW 24                    // bf16 per state row (48B, 16B-aligned)
#define SBUF (1025 * SROW)         // +1 zero row
#define TREE_LDS_BYTES (2 * SBUF * 2)   // 98400 B

#define TROW 520                   // transpose-stage LDS row stride (shorts)

typedef float f32x4 __attribute__((ext_vector_type(4)));
typedef short bf16x8 __attribute__((ext_vector_type(8)));
typedef unsigned long long u64;

__device__ __forceinline__ unsigned short f2b(float f) {
    union { __hip_bfloat16 h; unsigned short u; } cv;
    cv.h = __float2bfloat16(f);          // RNE, hardware v_cvt
    return cv.u;
}
__device__ __forceinline__ unsigned int pk(float lo, float hi) {
    return (unsigned int)f2b(lo) | ((unsigned int)f2b(hi) << 16);
}

// ---------------- Kernel 1: tree via MFMA + fused w1 convert/permute (R25) ----------
__launch_bounds__(1024, 4)
__global__ void tree_kernel(const float* __restrict__ x,
                            const float* __restrict__ leaf_w,
                            const float* __restrict__ leaf_b,
                            const float* __restrict__ conv_w,
                            const float* __restrict__ conv_b,
                            const float* __restrict__ bn_gamma,
                            const float* __restrict__ bn_beta,
                            const float* __restrict__ node_w,
                            unsigned short* __restrict__ pooledb,
                            const float* __restrict__ w1,
                            unsigned short* __restrict__ w1p) {
    extern __shared__ short smem[];
    short* buf0 = smem;
    short* buf1 = smem + SBUF;

    const int b   = blockIdx.x;
    const int tid = threadIdx.x;
    const int lane = tid & 63;
    const int wv   = tid >> 6;
    const int n    = lane & 15;
    const int g    = lane >> 4;

    if (tid < SROW) {
        buf0[1024 * SROW + tid] = 0;
        buf1[1024 * SROW + tid] = 0;
    }

    bf16x8 A1, A2;
#pragma unroll
    for (int j = 0; j < 8; ++j) {
        const int ci = (g & 1) * 8 + j;
        A1[j] = (short)f2b(conv_w[(n * C + ci) * 3 + (g >> 1)]);
        A2[j] = (g < 2) ? (short)f2b(conv_w[(n * C + ci) * 3 + 2]) : (short)0;
    }
    float sc4[4], bt4[4];
#pragma unroll
    for (int r = 0; r < 4; ++r) {
        const int co = g * 4 + r;
        float s = bn_gamma[co] / sqrtf(1.0f + 1e-5f);
        sc4[r] = s;
        bt4[r] = conv_b[co] * s + bn_beta[co];
    }

    // ---- leaf stage: 1 position per thread ----
    {
        const float xv = x[b * L + tid];
        const float nw = node_w[tid];
        const float4* lwa = (const float4*)(leaf_w + 16 * tid);
        const float4* lba = (const float4*)(leaf_b + 16 * tid);
        short* row = buf0 + tid * SROW;
#pragma unroll 1
        for (int q = 0; q < 4; ++q) {
            float4 wq = lwa[q], bq = lba[q];
            float v0 = (xv * wq.x + bq.x) * nw;
            float v1 = (xv * wq.y + bq.y) * nw;
            float v2 = (xv * wq.z + bq.z) * nw;
            float v3 = (xv * wq.w + bq.w) * nw;
            *(u64*)(row + 4 * q) =
                (u64)pk(v0, v1) | ((u64)pk(v2, v3) << 32);
            float p0 = fmaxf(v0, __shfl_xor(v0, 1));
            float p1 = fmaxf(v1, __shfl_xor(v1, 1));
            float p2 = fmaxf(v2, __shfl_xor(v2, 1));
            float p3 = fmaxf(v3, __shfl_xor(v3, 1));
            if (!(tid & 1)) {
                *(u64*)(pooledb + (long)b * FDIM + (tid >> 1) * 16 + 4 * q) =
                    (u64)pk(p0, p1) | ((u64)pk(p2, p3) << 32);
            }
        }
        __syncthreads();   // zero rows + leaf state visible to all waves
    }

    // ---- 10 levels via MFMA ----
    short* bin  = buf0;
    short* bout = buf1;
    int noff = L;
    for (int d = 0; d < 10; ++d) {
        const int sh = d + 1;
        const int mask = (1 << sh) - 1;

        bf16x8 B1s[4], B2s[4];
#pragma unroll
        for (int ti = 0; ti < 4; ++ti) {
            const int pos = (wv * 4 + ti) * 16 + n;
            const bool ok1 = (g >= 2) || ((pos & mask) != 0);
            const int r1 = ok1 ? (pos + (g >> 1) - 1) : 1024;
            B1s[ti] = *(const bf16x8*)(bin + r1 * SROW + (g & 1) * 8);
            const bool ok2 = ((pos & mask) != mask);
            const int r2 = ok2 ? (pos + 1) : 1024;
            B2s[ti] = *(const bf16x8*)(bin + r2 * SROW + (g & 1) * 8);
        }

#pragma unroll
        for (int ti = 0; ti < 4; ++ti) {
            const int pos = (wv * 4 + ti) * 16 + n;

            f32x4 acc = {0.f, 0.f, 0.f, 0.f};
            acc = __builtin_amdgcn_mfma_f32_16x16x32_bf16(A1, B1s[ti], acc, 0, 0, 0);
            acc = __builtin_amdgcn_mfma_f32_16x16x32_bf16(A2, B2s[ti], acc, 0, 0, 0);

            const float nwv = node_w[noff + (pos >> sh)];
            float z[4];
#pragma unroll
            for (int r = 0; r < 4; ++r)
                z[r] = fmaxf(fmaf(sc4[r], acc[r], bt4[r]), 0.f) * nwv;

            if (d < 9) {
                *(u64*)(bout + pos * SROW + g * 4) =
                    (u64)pk(z[0], z[1]) | ((u64)pk(z[2], z[3]) << 32);
            }

            float pz0 = fmaxf(z[0], __shfl_xor(z[0], 1));
            float pz1 = fmaxf(z[1], __shfl_xor(z[1], 1));
            float pz2 = fmaxf(z[2], __shfl_xor(z[2], 1));
            float pz3 = fmaxf(z[3], __shfl_xor(z[3], 1));
            if (!(n & 1)) {
                *(u64*)(pooledb + (long)b * FDIM + sh * 8192 + (pos >> 1) * 16 + g * 4) =
                    (u64)pk(pz0, pz1) | ((u64)pk(pz2, pz3) << 32);
            }
        }

        if (d >= 5 && d < 9) {
            __syncthreads();
        } else {
            asm volatile("s_waitcnt lgkmcnt(0)" ::: "memory");
        }

        short* t = bin; bin = bout; bout = t;
        noff += (512 >> d);
    }

    __syncthreads();   // protect smem reuse below

    // ---- tail: w1 f32 -> bf16 with feature permutation (grid-stride units) ----
    unsigned short* st = (unsigned short*)smem;   // [16][TROW] staging
    for (int unit = b; unit < 11 * H1; unit += BATCH) {
        const int lev = unit >> 7;
        const int nr  = unit & 127;
        const float* src = w1 + (long)nr * FDIM + lev * POOL;
#pragma unroll 2
        for (int i = tid; i < 2048; i += 1024) {       // i = c*128 + q (float4)
            const int c = i >> 7, q = i & 127;
            float4 v = *(const float4*)(src + (long)c * PCOLS + 4 * q);
            *(u64*)(st + c * TROW + 4 * q) =
                (u64)pk(v.x, v.y) | ((u64)pk(v.z, v.w) << 32);
        }
        __syncthreads();
#pragma unroll 2
        for (int i = tid; i < 2048; i += 1024) {       // i = pos2*4 + c4 (u64)
            const int pos2 = i >> 2, c4 = i & 3;
            unsigned short s0 = st[(c4 * 4 + 0) * TROW + pos2];
            unsigned short s1 = st[(c4 * 4 + 1) * TROW + pos2];
            unsigned short s2 = st[(c4 * 4 + 2) * TROW + pos2];
            unsigned short s3 = st[(c4 * 4 + 3) * TROW + pos2];
            *(u64*)(w1p + (long)nr * FDIM + lev * 8192 + pos2 * 16 + c4 * 4) =
                (u64)s0 | ((u64)s1 << 16) | ((u64)s2 << 32) | ((u64)s3 << 48);
        }
        __syncthreads();
    }
}

// ---------------- Kernel 2: fc1 via MFMA, FULL 256x128 output per ks-block ---------
// grid = KS = 256 (1/CU); 512 thr = 8 waves; wave = 32 rows x 128 cols (acc[2][8]).
// pooled read ONCE (46MB), w1p once (23MB): b-frags wave-invariant -> L1 broadcast.
__launch_bounds__(512, 2)
__global__ void fc1_mfma(const unsigned short* __restrict__ pooledb,
                         const unsigned short* __restrict__ w1b,
                         float* __restrict__ partial) {
    const int ks  = blockIdx.x;          // 0..255

    const int tid  = threadIdx.x;
    const int wv   = tid >> 6;           // 0..7
    const int lane = tid & 63;
    const int lrow = lane & 15;
    const int lk   = (lane >> 4) * 8;

    const int m0 = wv * 32;
    const int kb = ks * KCHUNK;

    const unsigned short* ap0 = pooledb + (long)(m0 + lrow) * FDIM + kb + lk;
    const unsigned short* ap1 = ap0 + (long)16 * FDIM;
    const unsigned short* bp  = w1b + (long)lrow * FDIM + kb + lk;

    f32x4 acc[2][8];
#pragma unroll
    for (int i = 0; i < 2; ++i)
#pragma unroll
        for (int ct = 0; ct < 8; ++ct) acc[i][ct] = (f32x4){0.f, 0.f, 0.f, 0.f};

#pragma unroll 1
    for (int kk = 0; kk < KCHUNK; kk += 32) {
        bf16x8 a0 = *(const bf16x8*)(ap0 + kk);
        bf16x8 a1 = *(const bf16x8*)(ap1 + kk);
#pragma unroll
        for (int ct = 0; ct < 8; ++ct) {
            bf16x8 bv = *(const bf16x8*)(bp + (long)(ct * 16) * FDIM + kk);
            acc[0][ct] = __builtin_amdgcn_mfma_f32_16x16x32_bf16(a0, bv, acc[0][ct], 0, 0, 0);
            acc[1][ct] = __builtin_amdgcn_mfma_f32_16x16x32_bf16(a1, bv, acc[1][ct], 0, 0, 0);
        }
    }

    // C/D: col = lane&15, row = (lane>>4)*4 + reg  [m89-verified]
    // partial layout [row][ks][col] so fc_tail streams contiguously.
    const int rbase = (lane >> 4) * 4;
#pragma unroll
    for (int i = 0; i < 2; ++i) {
#pragma unroll
        for (int r = 0; r < 4; ++r) {
            const int row = m0 + i * 16 + rbase + r;
            float* p = partial + (long)row * (KS * H1) + ks * H1 + (lane & 15);
#pragma unroll
            for (int ct = 0; ct < 8; ++ct)
                p[ct * 16] = acc[i][ct][r];
        }
    }
}

// ---------------- Kernel 3: parallel partial-reduce + fc1 bias/relu + fc2 + fc3 --
// partial[b][ks][col]: block b streams its contiguous 128KB slice.
__launch_bounds__(1024)
__global__ void fc_tail(const float* __restrict__ partial,
                        const float* __restrict__ fc1_b,
                        const float* __restrict__ w2,
                        const float* __restrict__ b2,
                        const float* __restrict__ w3,
                        const float* __restrict__ b3,
                        float* __restrict__ out, int nkt) {
    __shared__ float red[8][H1];
    __shared__ float h1_s[H1];
    __shared__ float w2_s[H2 * 129];

    const int b = blockIdx.x;
    const int tid = threadIdx.x;
    const int t = tid & 127;      // h1 index
    const int q = tid >> 7;       // kt group 0..7

    const int per = nkt >> 3;     // 32
    float s = 0.f;
    const float* pb = partial + (long)b * (KS * H1) + (q * per) * H1 + t;
#pragma unroll 8
    for (int kt = 0; kt < per; ++kt)
        s += pb[kt * H1];
    red[q][t] = s;

    for (int i = tid; i < H2 * H1; i += 1024) {
        int j = i >> 7, k = i & 127;
        w2_s[j * 129 + k] = w2[i];
    }
    __syncthreads();

    if (tid < 128) {
        float ss = red[0][t] + red[1][t] + red[2][t] + red[3][t]
                 + red[4][t] + red[5][t] + red[6][t] + red[7][t];
        h1_s[t] = fmaxf(ss + fc1_b[t], 0.f);
    }
    __syncthreads();

    if (tid < 64) {
        float a2 = 0.f;
#pragma unroll 8
        for (int k = 0; k < H1; ++k) a2 = fmaf(h1_s[k], w2_s[tid * 129 + k], a2);
        float h2 = fmaxf(a2 + b2[tid], 0.f);
        float r = h2 * w3[tid];
#pragma unroll
        for (int off = 32; off > 0; off >>= 1) r += __shfl_down(r, off);
        if (tid == 0) out[b] = r + b3[0];
    }
}

extern "C" void kernel_launch(void* const* d_in, const int* in_sizes, int n_in,
                              void* d_out, int out_size, void* d_ws, size_t ws_size,
                              hipStream_t stream) {
    const float* x        = (const float*)d_in[0];
    const float* leaf_w   = (const float*)d_in[1];
    const float* leaf_b   = (const float*)d_in[2];
    const float* conv_w   = (const float*)d_in[3];
    const float* conv_b   = (const float*)d_in[4];
    const float* bn_gamma = (const float*)d_in[5];
    const float* bn_beta  = (const float*)d_in[6];
    const float* node_w   = (const float*)d_in[7];
    const float* fc1_w    = (const float*)d_in[8];
    const float* fc1_b    = (const float*)d_in[9];
    const float* fc2_w    = (const float*)d_in[10];
    const float* fc2_b    = (const float*)d_in[11];
    const float* fc3_w    = (const float*)d_in[12];
    const float* fc3_b    = (const float*)d_in[13];

    // ws: pooled bf16 (46.1MB) | w1p bf16 (23.1MB) | partial f32 (33.6MB) = 102.8MB
    unsigned short* pooledb = (unsigned short*)d_ws;
    unsigned short* w1p     = pooledb + (long)BATCH * FDIM;
    float*          partial = (float*)(w1p + (long)H1 * FDIM);

    (void)hipFuncSetAttribute((const void*)tree_kernel,
                        hipFuncAttributeMaxDynamicSharedMemorySize, TREE_LDS_BYTES);

    tree_kernel<<<BATCH, 1024, TREE_LDS_BYTES, stream>>>(
        x, leaf_w, leaf_b, conv_w, conv_b, bn_gamma, bn_beta, node_w, pooledb,
        fc1_w, w1p);

    fc1_mfma<<<KS, 512, 0, stream>>>(pooledb, w1p, partial);

    fc_tail<<<BATCH, 1024, 0, stream>>>(partial, fc1_b, fc2_w, fc2_b, fc3_w, fc3_b,
                                        (float*)d_out, KS);
}

// Round 27
// 82.207 us; speedup vs baseline: 1.1267x; 1.0832x over previous
//
#include <hip/hip_runtime.h>
#include <hip/hip_bf16.h>

#define BATCH 256
#define L 1024
#define C 16
#define POOL 512
#define PCOLS 5632
#define FDIM 90112        // 11 levels * 8192
#define H1 128
#define H2 64

#define KS 256            // split-K factor for fc1 mfma GEMM
#define KCHUNK (FDIM / KS)   // 352

#define SROW 24                    // bf16 per state row (48B, 16B-aligned)
#define SBUF (1025 * SROW)         // +1 zero row
#define TREE_LDS_BYTES (2 * SBUF * 2 + 2047 * 4)   // bufs + node_w cache

typedef float f32x4 __attribute__((ext_vector_type(4)));
typedef short bf16x8 __attribute__((ext_vector_type(8)));
typedef unsigned long long u64;

__device__ __forceinline__ unsigned short f2b(float f) {
    union { __hip_bfloat16 h; unsigned short u; } cv;
    cv.h = __float2bfloat16(f);          // RNE, hardware v_cvt
    return cv.u;
}
__device__ __forceinline__ unsigned int pk(float lo, float hi) {
    return (unsigned int)f2b(lo) | ((unsigned int)f2b(hi) << 16);
}

// ---------------- Kernel 1: tree via MFMA, w1 permute INTERLEAVED into levels ------
// pooled layout: f_new = level*8192 + pos2*16 + c   (w1 permuted to match).
// w1 permute = 11 register-only streaming rounds (no LDS), one per level, issued
// right after each sync so their VMEM latency hides under the tree's dep chain.
__launch_bounds__(1024, 4)
__global__ void tree_kernel(const float* __restrict__ x,
                            const float* __restrict__ leaf_w,
                            const float* __restrict__ leaf_b,
                            const float* __restrict__ conv_w,
                            const float* __restrict__ conv_b,
                            const float* __restrict__ bn_gamma,
                            const float* __restrict__ bn_beta,
                            const float* __restrict__ node_w,
                            unsigned short* __restrict__ pooledb,
                            const float* __restrict__ w1,
                            unsigned short* __restrict__ w1p) {
    extern __shared__ short smem[];
    short* buf0 = smem;
    short* buf1 = smem + SBUF;
    float* nwl  = (float*)(smem + 2 * SBUF);   // node_w cache (2047 floats)

    const int b   = blockIdx.x;
    const int tid = threadIdx.x;
    const int lane = tid & 63;
    const int wv   = tid >> 6;
    const int n    = lane & 15;
    const int g    = lane >> 4;

    if (tid < SROW) {
        buf0[1024 * SROW + tid] = 0;
        buf1[1024 * SROW + tid] = 0;
    }
    for (int i = tid; i < 2047; i += 1024) nwl[i] = node_w[i];

    bf16x8 A1, A2;
#pragma unroll
    for (int j = 0; j < 8; ++j) {
        const int ci = (g & 1) * 8 + j;
        A1[j] = (short)f2b(conv_w[(n * C + ci) * 3 + (g >> 1)]);
        A2[j] = (g < 2) ? (short)f2b(conv_w[(n * C + ci) * 3 + 2]) : (short)0;
    }
    float sc4[4], bt4[4];
#pragma unroll
    for (int r = 0; r < 4; ++r) {
        const int co = g * 4 + r;
        float s = bn_gamma[co] / sqrtf(1.0f + 1e-5f);
        sc4[r] = s;
        bt4[r] = conv_b[co] * s + bn_beta[co];
    }

    // permute round helper state: per round, thread handles one u64 of w1p
    // gidx = b*11264 + j*1024 + tid ; decompose (lev, nr, c4, pos2)
    const int gbase = b * 11264 + tid;

    // ---- leaf stage: 1 position per thread ----
    {
        const float xv = x[b * L + tid];
        const float nw = node_w[tid];
        const float4* lwa = (const float4*)(leaf_w + 16 * tid);
        const float4* lba = (const float4*)(leaf_b + 16 * tid);
        short* row = buf0 + tid * SROW;
#pragma unroll 1
        for (int q = 0; q < 4; ++q) {
            float4 wq = lwa[q], bq = lba[q];
            float v0 = (xv * wq.x + bq.x) * nw;
            float v1 = (xv * wq.y + bq.y) * nw;
            float v2 = (xv * wq.z + bq.z) * nw;
            float v3 = (xv * wq.w + bq.w) * nw;
            *(u64*)(row + 4 * q) =
                (u64)pk(v0, v1) | ((u64)pk(v2, v3) << 32);
            float p0 = fmaxf(v0, __shfl_xor(v0, 1));
            float p1 = fmaxf(v1, __shfl_xor(v1, 1));
            float p2 = fmaxf(v2, __shfl_xor(v2, 1));
            float p3 = fmaxf(v3, __shfl_xor(v3, 1));
            if (!(tid & 1)) {
                *(u64*)(pooledb + (long)b * FDIM + (tid >> 1) * 16 + 4 * q) =
                    (u64)pk(p0, p1) | ((u64)pk(p2, p3) << 32);
            }
        }
        __syncthreads();   // zero rows + nwl + leaf state visible to all waves
    }

    // ---- 10 levels via MFMA, one permute round interleaved per level ----
    short* bin  = buf0;
    short* bout = buf1;
    int noff = L;
    for (int d = 0; d < 10; ++d) {
        const int sh = d + 1;
        const int mask = (1 << sh) - 1;

        // --- permute round d: issue streaming loads early (hide under level) ---
        {
            const int gidx = gbase + d * 1024;
            const int pos2 = gidx & 511;
            const int c4   = (gidx >> 9) & 3;
            const int un   = gidx >> 11;          // 0..1407
            const int lev  = un >> 7;
            const int nr   = un & 127;
            const float* src = w1 + (long)nr * FDIM + lev * POOL + pos2;
            float f0 = src[(c4 * 4 + 0) * PCOLS];
            float f1 = src[(c4 * 4 + 1) * PCOLS];
            float f2 = src[(c4 * 4 + 2) * PCOLS];
            float f3 = src[(c4 * 4 + 3) * PCOLS];
            *(u64*)(w1p + (long)nr * FDIM + lev * 8192 + pos2 * 16 + c4 * 4) =
                (u64)pk(f0, f1) | ((u64)pk(f2, f3) << 32);
        }

        // --- tree level ---
        bf16x8 B1s[4], B2s[4];
#pragma unroll
        for (int ti = 0; ti < 4; ++ti) {
            const int pos = (wv * 4 + ti) * 16 + n;
            const bool ok1 = (g >= 2) || ((pos & mask) != 0);
            const int r1 = ok1 ? (pos + (g >> 1) - 1) : 1024;
            B1s[ti] = *(const bf16x8*)(bin + r1 * SROW + (g & 1) * 8);
            const bool ok2 = ((pos & mask) != mask);
            const int r2 = ok2 ? (pos + 1) : 1024;
            B2s[ti] = *(const bf16x8*)(bin + r2 * SROW + (g & 1) * 8);
        }

#pragma unroll
        for (int ti = 0; ti < 4; ++ti) {
            const int pos = (wv * 4 + ti) * 16 + n;

            f32x4 acc = {0.f, 0.f, 0.f, 0.f};
            acc = __builtin_amdgcn_mfma_f32_16x16x32_bf16(A1, B1s[ti], acc, 0, 0, 0);
            acc = __builtin_amdgcn_mfma_f32_16x16x32_bf16(A2, B2s[ti], acc, 0, 0, 0);

            const float nwv = nwl[noff + (pos >> sh)];
            float z[4];
#pragma unroll
            for (int r = 0; r < 4; ++r)
                z[r] = fmaxf(fmaf(sc4[r], acc[r], bt4[r]), 0.f) * nwv;

            if (d < 9) {
                *(u64*)(bout + pos * SROW + g * 4) =
                    (u64)pk(z[0], z[1]) | ((u64)pk(z[2], z[3]) << 32);
            }

            float pz0 = fmaxf(z[0], __shfl_xor(z[0], 1));
            float pz1 = fmaxf(z[1], __shfl_xor(z[1], 1));
            float pz2 = fmaxf(z[2], __shfl_xor(z[2], 1));
            float pz3 = fmaxf(z[3], __shfl_xor(z[3], 1));
            if (!(n & 1)) {
                *(u64*)(pooledb + (long)b * FDIM + sh * 8192 + (pos >> 1) * 16 + g * 4) =
                    (u64)pk(pz0, pz1) | ((u64)pk(pz2, pz3) << 32);
            }
        }

        if (d >= 5 && d < 9) {
            __syncthreads();
        } else {
            asm volatile("s_waitcnt lgkmcnt(0)" ::: "memory");
        }

        short* t = bin; bin = bout; bout = t;
        noff += (512 >> d);
    }

    // --- final permute round (j = 10) ---
    {
        const int gidx = gbase + 10 * 1024;
        const int pos2 = gidx & 511;
        const int c4   = (gidx >> 9) & 3;
        const int un   = gidx >> 11;
        const int lev  = un >> 7;
        const int nr   = un & 127;
        const float* src = w1 + (long)nr * FDIM + lev * POOL + pos2;
        float f0 = src[(c4 * 4 + 0) * PCOLS];
        float f1 = src[(c4 * 4 + 1) * PCOLS];
        float f2 = src[(c4 * 4 + 2) * PCOLS];
        float f3 = src[(c4 * 4 + 3) * PCOLS];
        *(u64*)(w1p + (long)nr * FDIM + lev * 8192 + pos2 * 16 + c4 * 4) =
            (u64)pk(f0, f1) | ((u64)pk(f2, f3) << 32);
    }
}

// ---------------- Kernel 2: fc1 via MFMA, FULL 256x128 output per ks-block ---------
__launch_bounds__(512, 2)
__global__ void fc1_mfma(const unsigned short* __restrict__ pooledb,
                         const unsigned short* __restrict__ w1b,
                         float* __restrict__ partial) {
    const int ks  = blockIdx.x;          // 0..255

    const int tid  = threadIdx.x;
    const int wv   = tid >> 6;           // 0..7
    const int lane = tid & 63;
    const int lrow = lane & 15;
    const int lk   = (lane >> 4) * 8;

    const int m0 = wv * 32;
    const int kb = ks * KCHUNK;

    const unsigned short* ap0 = pooledb + (long)(m0 + lrow) * FDIM + kb + lk;
    const unsigned short* ap1 = ap0 + (long)16 * FDIM;
    const unsigned short* bp  = w1b + (long)lrow * FDIM + kb + lk;

    f32x4 acc[2][8];
#pragma unroll
    for (int i = 0; i < 2; ++i)
#pragma unroll
        for (int ct = 0; ct < 8; ++ct) acc[i][ct] = (f32x4){0.f, 0.f, 0.f, 0.f};

#pragma unroll 1
    for (int kk = 0; kk < KCHUNK; kk += 32) {
        bf16x8 a0 = *(const bf16x8*)(ap0 + kk);
        bf16x8 a1 = *(const bf16x8*)(ap1 + kk);
#pragma unroll
        for (int ct = 0; ct < 8; ++ct) {
            bf16x8 bv = *(const bf16x8*)(bp + (long)(ct * 16) * FDIM + kk);
            acc[0][ct] = __builtin_amdgcn_mfma_f32_16x16x32_bf16(a0, bv, acc[0][ct], 0, 0, 0);
            acc[1][ct] = __builtin_amdgcn_mfma_f32_16x16x32_bf16(a1, bv, acc[1][ct], 0, 0, 0);
        }
    }

    const int rbase = (lane >> 4) * 4;
#pragma unroll
    for (int i = 0; i < 2; ++i) {
#pragma unroll
        for (int r = 0; r < 4; ++r) {
            const int row = m0 + i * 16 + rbase + r;
            float* p = partial + (long)row * (KS * H1) + ks * H1 + (lane & 15);
#pragma unroll
            for (int ct = 0; ct < 8; ++ct)
                p[ct * 16] = acc[i][ct][r];
        }
    }
}

// ---------------- Kernel 3: parallel partial-reduce + fc1 bias/relu + fc2 + fc3 --
__launch_bounds__(1024)
__global__ void fc_tail(const float* __restrict__ partial,
                        const float* __restrict__ fc1_b,
                        const float* __restrict__ w2,
                        const float* __restrict__ b2,
                        const float* __restrict__ w3,
                        const float* __restrict__ b3,
                        float* __restrict__ out, int nkt) {
    __shared__ float red[8][H1];
    __shared__ float h1_s[H1];
    __shared__ float w2_s[H2 * 129];

    const int b = blockIdx.x;
    const int tid = threadIdx.x;
    const int t = tid & 127;      // h1 index
    const int q = tid >> 7;       // kt group 0..7

    const int per = nkt >> 3;     // 32
    float s = 0.f;
    const float* pb = partial + (long)b * (KS * H1) + (q * per) * H1 + t;
#pragma unroll 8
    for (int kt = 0; kt < per; ++kt)
        s += pb[kt * H1];
    red[q][t] = s;

    for (int i = tid; i < H2 * H1; i += 1024) {
        int j = i >> 7, k = i & 127;
        w2_s[j * 129 + k] = w2[i];
    }
    __syncthreads();

    if (tid < 128) {
        float ss = red[0][t] + red[1][t] + red[2][t] + red[3][t]
                 + red[4][t] + red[5][t] + red[6][t] + red[7][t];
        h1_s[t] = fmaxf(ss + fc1_b[t], 0.f);
    }
    __syncthreads();

    if (tid < 64) {
        float a2 = 0.f;
#pragma unroll 8
        for (int k = 0; k < H1; ++k) a2 = fmaf(h1_s[k], w2_s[tid * 129 + k], a2);
        float h2 = fmaxf(a2 + b2[tid], 0.f);
        float r = h2 * w3[tid];
#pragma unroll
        for (int off = 32; off > 0; off >>= 1) r += __shfl_down(r, off);
        if (tid == 0) out[b] = r + b3[0];
    }
}

extern "C" void kernel_launch(void* const* d_in, const int* in_sizes, int n_in,
                              void* d_out, int out_size, void* d_ws, size_t ws_size,
                              hipStream_t stream) {
    const float* x        = (const float*)d_in[0];
    const float* leaf_w   = (const float*)d_in[1];
    const float* leaf_b   = (const float*)d_in[2];
    const float* conv_w   = (const float*)d_in[3];
    const float* conv_b   = (const float*)d_in[4];
    const float* bn_gamma = (const float*)d_in[5];
    const float* bn_beta  = (const float*)d_in[6];
    const float* node_w   = (const float*)d_in[7];
    const float* fc1_w    = (const float*)d_in[8];
    const float* fc1_b    = (const float*)d_in[9];
    const float* fc2_w    = (const float*)d_in[10];
    const float* fc2_b    = (const float*)d_in[11];
    const float* fc3_w    = (const float*)d_in[12];
    const float* fc3_b    = (const float*)d_in[13];

    // ws: pooled bf16 (46.1MB) | w1p bf16 (23.1MB) | partial f32 (33.6MB) = 102.8MB
    unsigned short* pooledb = (unsigned short*)d_ws;
    unsigned short* w1p     = pooledb + (long)BATCH * FDIM;
    float*          partial = (float*)(w1p + (long)H1 * FDIM);

    (void)hipFuncSetAttribute((const void*)tree_kernel,
                        hipFuncAttributeMaxDynamicSharedMemorySize, TREE_LDS_BYTES);

    tree_kernel<<<BATCH, 1024, TREE_LDS_BYTES, stream>>>(
        x, leaf_w, leaf_b, conv_w, conv_b, bn_gamma, bn_beta, node_w, pooledb,
        fc1_w, w1p);

    fc1_mfma<<<KS, 512, 0, stream>>>(pooledb, w1p, partial);

    fc_tail<<<BATCH, 1024, 0, stream>>>(partial, fc1_b, fc2_w, fc2_b, fc3_w, fc3_b,
                                        (float*)d_out, KS);
}

// Round 28
// 79.361 us; speedup vs baseline: 1.1671x; 1.0359x over previous
//
#include <hip/hip_runtime.h>
#include <hip/hip_bf16.h>

#define BATCH 256
#define L 1024
#define C 16
#define POOL 512
#define PCOLS 5632
#define FDIM 90112        // 11 levels * 8192
#define H1 128
#define H2 64

#define KS 256            // split-K factor for fc1 mfma GEMM
#define KCHUNK (FDIM / KS)   // 352

#define SROW 24                    // bf16 per state row (48B, 16B-aligned)
#define SBUF (1025 * SROW)         // +1 zero row
#define TREE_LDS_BYTES (2 * SBUF * 2 + 2047 * 4)   // bufs + node_w cache

typedef float f32x4 __attribute__((ext_vector_type(4)));
typedef short bf16x8 __attribute__((ext_vector_type(8)));
typedef unsigned long long u64;

__device__ __forceinline__ unsigned short f2b(float f) {
    union { __hip_bfloat16 h; unsigned short u; } cv;
    cv.h = __float2bfloat16(f);          // RNE, hardware v_cvt
    return cv.u;
}
__device__ __forceinline__ unsigned int pk(float lo, float hi) {
    return (unsigned int)f2b(lo) | ((unsigned int)f2b(hi) << 16);
}

// ---------------- Kernel 1: tree via MFMA, w1 permute interleaved (R27-proven) -----
__launch_bounds__(1024, 4)
__global__ void tree_kernel(const float* __restrict__ x,
                            const float* __restrict__ leaf_w,
                            const float* __restrict__ leaf_b,
                            const float* __restrict__ conv_w,
                            const float* __restrict__ conv_b,
                            const float* __restrict__ bn_gamma,
                            const float* __restrict__ bn_beta,
                            const float* __restrict__ node_w,
                            unsigned short* __restrict__ pooledb,
                            const float* __restrict__ w1,
                            unsigned short* __restrict__ w1p) {
    extern __shared__ short smem[];
    short* buf0 = smem;
    short* buf1 = smem + SBUF;
    float* nwl  = (float*)(smem + 2 * SBUF);   // node_w cache (2047 floats)

    const int b   = blockIdx.x;
    const int tid = threadIdx.x;
    const int lane = tid & 63;
    const int wv   = tid >> 6;
    const int n    = lane & 15;
    const int g    = lane >> 4;

    if (tid < SROW) {
        buf0[1024 * SROW + tid] = 0;
        buf1[1024 * SROW + tid] = 0;
    }
    for (int i = tid; i < 2047; i += 1024) nwl[i] = node_w[i];

    bf16x8 A1, A2;
#pragma unroll
    for (int j = 0; j < 8; ++j) {
        const int ci = (g & 1) * 8 + j;
        A1[j] = (short)f2b(conv_w[(n * C + ci) * 3 + (g >> 1)]);
        A2[j] = (g < 2) ? (short)f2b(conv_w[(n * C + ci) * 3 + 2]) : (short)0;
    }
    float sc4[4], bt4[4];
#pragma unroll
    for (int r = 0; r < 4; ++r) {
        const int co = g * 4 + r;
        float s = bn_gamma[co] / sqrtf(1.0f + 1e-5f);
        sc4[r] = s;
        bt4[r] = conv_b[co] * s + bn_beta[co];
    }

    const int gbase = b * 11264 + tid;

    // ---- leaf stage: 1 position per thread ----
    {
        const float xv = x[b * L + tid];
        const float nw = node_w[tid];
        const float4* lwa = (const float4*)(leaf_w + 16 * tid);
        const float4* lba = (const float4*)(leaf_b + 16 * tid);
        short* row = buf0 + tid * SROW;
#pragma unroll 1
        for (int q = 0; q < 4; ++q) {
            float4 wq = lwa[q], bq = lba[q];
            float v0 = (xv * wq.x + bq.x) * nw;
            float v1 = (xv * wq.y + bq.y) * nw;
            float v2 = (xv * wq.z + bq.z) * nw;
            float v3 = (xv * wq.w + bq.w) * nw;
            *(u64*)(row + 4 * q) =
                (u64)pk(v0, v1) | ((u64)pk(v2, v3) << 32);
            float p0 = fmaxf(v0, __shfl_xor(v0, 1));
            float p1 = fmaxf(v1, __shfl_xor(v1, 1));
            float p2 = fmaxf(v2, __shfl_xor(v2, 1));
            float p3 = fmaxf(v3, __shfl_xor(v3, 1));
            if (!(tid & 1)) {
                *(u64*)(pooledb + (long)b * FDIM + (tid >> 1) * 16 + 4 * q) =
                    (u64)pk(p0, p1) | ((u64)pk(p2, p3) << 32);
            }
        }
        __syncthreads();   // zero rows + nwl + leaf state visible to all waves
    }

    // ---- 10 levels via MFMA, one permute round interleaved per level ----
    short* bin  = buf0;
    short* bout = buf1;
    int noff = L;
    for (int d = 0; d < 10; ++d) {
        const int sh = d + 1;
        const int mask = (1 << sh) - 1;

        // --- permute round d (VMEM latency hides under the level's LDS/MFMA) ---
        {
            const int gidx = gbase + d * 1024;
            const int pos2 = gidx & 511;
            const int c4   = (gidx >> 9) & 3;
            const int un   = gidx >> 11;          // 0..1407
            const int lev  = un >> 7;
            const int nr   = un & 127;
            const float* src = w1 + (long)nr * FDIM + lev * POOL + pos2;
            float f0 = src[(c4 * 4 + 0) * PCOLS];
            float f1 = src[(c4 * 4 + 1) * PCOLS];
            float f2 = src[(c4 * 4 + 2) * PCOLS];
            float f3 = src[(c4 * 4 + 3) * PCOLS];
            *(u64*)(w1p + (long)nr * FDIM + lev * 8192 + pos2 * 16 + c4 * 4) =
                (u64)pk(f0, f1) | ((u64)pk(f2, f3) << 32);
        }

        // --- tree level ---
        bf16x8 B1s[4], B2s[4];
#pragma unroll
        for (int ti = 0; ti < 4; ++ti) {
            const int pos = (wv * 4 + ti) * 16 + n;
            const bool ok1 = (g >= 2) || ((pos & mask) != 0);
            const int r1 = ok1 ? (pos + (g >> 1) - 1) : 1024;
            B1s[ti] = *(const bf16x8*)(bin + r1 * SROW + (g & 1) * 8);
            const bool ok2 = ((pos & mask) != mask);
            const int r2 = ok2 ? (pos + 1) : 1024;
            B2s[ti] = *(const bf16x8*)(bin + r2 * SROW + (g & 1) * 8);
        }

#pragma unroll
        for (int ti = 0; ti < 4; ++ti) {
            const int pos = (wv * 4 + ti) * 16 + n;

            f32x4 acc = {0.f, 0.f, 0.f, 0.f};
            acc = __builtin_amdgcn_mfma_f32_16x16x32_bf16(A1, B1s[ti], acc, 0, 0, 0);
            acc = __builtin_amdgcn_mfma_f32_16x16x32_bf16(A2, B2s[ti], acc, 0, 0, 0);

            const float nwv = nwl[noff + (pos >> sh)];
            float z[4];
#pragma unroll
            for (int r = 0; r < 4; ++r)
                z[r] = fmaxf(fmaf(sc4[r], acc[r], bt4[r]), 0.f) * nwv;

            if (d < 9) {
                *(u64*)(bout + pos * SROW + g * 4) =
                    (u64)pk(z[0], z[1]) | ((u64)pk(z[2], z[3]) << 32);
            }

            float pz0 = fmaxf(z[0], __shfl_xor(z[0], 1));
            float pz1 = fmaxf(z[1], __shfl_xor(z[1], 1));
            float pz2 = fmaxf(z[2], __shfl_xor(z[2], 1));
            float pz3 = fmaxf(z[3], __shfl_xor(z[3], 1));
            if (!(n & 1)) {
                *(u64*)(pooledb + (long)b * FDIM + sh * 8192 + (pos >> 1) * 16 + g * 4) =
                    (u64)pk(pz0, pz1) | ((u64)pk(pz2, pz3) << 32);
            }
        }

        if (d >= 5 && d < 9) {
            __syncthreads();
        } else {
            asm volatile("s_waitcnt lgkmcnt(0)" ::: "memory");
        }

        short* t = bin; bin = bout; bout = t;
        noff += (512 >> d);
    }

    // --- final permute round (j = 10) ---
    {
        const int gidx = gbase + 10 * 1024;
        const int pos2 = gidx & 511;
        const int c4   = (gidx >> 9) & 3;
        const int un   = gidx >> 11;
        const int lev  = un >> 7;
        const int nr   = un & 127;
        const float* src = w1 + (long)nr * FDIM + lev * POOL + pos2;
        float f0 = src[(c4 * 4 + 0) * PCOLS];
        float f1 = src[(c4 * 4 + 1) * PCOLS];
        float f2 = src[(c4 * 4 + 2) * PCOLS];
        float f3 = src[(c4 * 4 + 3) * PCOLS];
        *(u64*)(w1p + (long)nr * FDIM + lev * 8192 + pos2 * 16 + c4 * 4) =
            (u64)pk(f0, f1) | ((u64)pk(f2, f3) << 32);
    }
}

// ---------------- Kernel 2: fc1 via MFMA, full 256x128/block, BF16 partials --------
// partial layout [row][ks][64 x u32(bf16 pair)]; even lane stores i=0 row's pair,
// odd lane reconstructs the identical pack for i=1's row -> all 64 lanes store.
__launch_bounds__(512, 2)
__global__ void fc1_mfma(const unsigned short* __restrict__ pooledb,
                         const unsigned short* __restrict__ w1b,
                         unsigned int* __restrict__ p32) {
    const int ks  = blockIdx.x;          // 0..255

    const int tid  = threadIdx.x;
    const int wv   = tid >> 6;           // 0..7
    const int lane = tid & 63;
    const int lrow = lane & 15;
    const int lk   = (lane >> 4) * 8;

    const int m0 = wv * 32;
    const int kb = ks * KCHUNK;

    const unsigned short* ap0 = pooledb + (long)(m0 + lrow) * FDIM + kb + lk;
    const unsigned short* ap1 = ap0 + (long)16 * FDIM;
    const unsigned short* bp  = w1b + (long)lrow * FDIM + kb + lk;

    f32x4 acc[2][8];
#pragma unroll
    for (int i = 0; i < 2; ++i)
#pragma unroll
        for (int ct = 0; ct < 8; ++ct) acc[i][ct] = (f32x4){0.f, 0.f, 0.f, 0.f};

#pragma unroll 1
    for (int kk = 0; kk < KCHUNK; kk += 32) {
        bf16x8 a0 = *(const bf16x8*)(ap0 + kk);
        bf16x8 a1 = *(const bf16x8*)(ap1 + kk);
#pragma unroll
        for (int ct = 0; ct < 8; ++ct) {
            bf16x8 bv = *(const bf16x8*)(bp + (long)(ct * 16) * FDIM + kk);
            acc[0][ct] = __builtin_amdgcn_mfma_f32_16x16x32_bf16(a0, bv, acc[0][ct], 0, 0, 0);
            acc[1][ct] = __builtin_amdgcn_mfma_f32_16x16x32_bf16(a1, bv, acc[1][ct], 0, 0, 0);
        }
    }

    // C/D: col = lane&15, row = (lane>>4)*4 + reg  [m89-verified]
    const int rbase = (lane >> 4) * 4;
    const int half  = lane & 1;          // 0 -> i=0 rows, 1 -> i=1 rows
    const int cpair = (lane & 15) >> 1;
#pragma unroll
    for (int r = 0; r < 4; ++r) {
        const int row = m0 + (half << 4) + rbase + r;
        unsigned int* p = p32 + (long)row * (KS * 64) + ks * 64 + cpair;
#pragma unroll
        for (int ct = 0; ct < 8; ++ct) {
            float x0 = acc[0][ct][r], x1 = acc[1][ct][r];
            float y0 = __shfl_xor(x0, 1), y1 = __shfl_xor(x1, 1);
            float lo = half ? y1 : x0;
            float hi = half ? x1 : y0;
            p[ct * 8] = pk(lo, hi);
        }
    }
}

// ---------------- Kernel 3: bf16 partial-reduce + fc1 bias/relu + fc2 + fc3 -------
// partial[b][ks][64 u32]: block b streams its contiguous 64KB slice.
__launch_bounds__(1024)
__global__ void fc_tail(const unsigned int* __restrict__ p32,
                        const float* __restrict__ fc1_b,
                        const float* __restrict__ w2,
                        const float* __restrict__ b2,
                        const float* __restrict__ w3,
                        const float* __restrict__ b3,
                        float* __restrict__ out) {
    __shared__ float red[16][H1];
    __shared__ float h1_s[H1];
    __shared__ float w2_s[H2 * 129];

    const int b = blockIdx.x;
    const int tid = threadIdx.x;
    const int t2 = tid & 63;      // col pair (cols 2*t2, 2*t2+1)
    const int q  = tid >> 6;      // ks group 0..15 (16 ks each)

    float s0 = 0.f, s1 = 0.f;
    const unsigned int* pb = p32 + (long)b * (KS * 64) + (q * 16) * 64 + t2;
#pragma unroll
    for (int kt = 0; kt < 16; ++kt) {
        unsigned int v = pb[kt * 64];
        union { unsigned int u; float f; } lo, hi;
        lo.u = v << 16;
        hi.u = v & 0xffff0000u;
        s0 += lo.f;
        s1 += hi.f;
    }
    red[q][2 * t2]     = s0;
    red[q][2 * t2 + 1] = s1;

    for (int i = tid; i < H2 * H1; i += 1024) {
        int j = i >> 7, k = i & 127;
        w2_s[j * 129 + k] = w2[i];
    }
    __syncthreads();

    if (tid < 128) {
        float ss = 0.f;
#pragma unroll
        for (int qq = 0; qq < 16; ++qq) ss += red[qq][tid];
        h1_s[tid] = fmaxf(ss + fc1_b[tid], 0.f);
    }
    __syncthreads();

    if (tid < 64) {
        float a2 = 0.f;
#pragma unroll 8
        for (int k = 0; k < H1; ++k) a2 = fmaf(h1_s[k], w2_s[tid * 129 + k], a2);
        float h2 = fmaxf(a2 + b2[tid], 0.f);
        float r = h2 * w3[tid];
#pragma unroll
        for (int off = 32; off > 0; off >>= 1) r += __shfl_down(r, off);
        if (tid == 0) out[b] = r + b3[0];
    }
}

extern "C" void kernel_launch(void* const* d_in, const int* in_sizes, int n_in,
                              void* d_out, int out_size, void* d_ws, size_t ws_size,
                              hipStream_t stream) {
    const float* x        = (const float*)d_in[0];
    const float* leaf_w   = (const float*)d_in[1];
    const float* leaf_b   = (const float*)d_in[2];
    const float* conv_w   = (const float*)d_in[3];
    const float* conv_b   = (const float*)d_in[4];
    const float* bn_gamma = (const float*)d_in[5];
    const float* bn_beta  = (const float*)d_in[6];
    const float* node_w   = (const float*)d_in[7];
    const float* fc1_w    = (const float*)d_in[8];
    const float* fc1_b    = (const float*)d_in[9];
    const float* fc2_w    = (const float*)d_in[10];
    const float* fc2_b    = (const float*)d_in[11];
    const float* fc3_w    = (const float*)d_in[12];
    const float* fc3_b    = (const float*)d_in[13];

    // ws: pooled bf16 (46.1MB) | w1p bf16 (23.1MB) | partial bf16 (16.8MB) = 86MB
    unsigned short* pooledb = (unsigned short*)d_ws;
    unsigned short* w1p     = pooledb + (long)BATCH * FDIM;
    unsigned int*   p32     = (unsigned int*)(w1p + (long)H1 * FDIM);

    (void)hipFuncSetAttribute((const void*)tree_kernel,
                        hipFuncAttributeMaxDynamicSharedMemorySize, TREE_LDS_BYTES);

    tree_kernel<<<BATCH, 1024, TREE_LDS_BYTES, stream>>>(
        x, leaf_w, leaf_b, conv_w, conv_b, bn_gamma, bn_beta, node_w, pooledb,
        fc1_w, w1p);

    fc1_mfma<<<KS, 512, 0, stream>>>(pooledb, w1p, p32);

    fc_tail<<<BATCH, 1024, 0, stream>>>(p32, fc1_b, fc2_w, fc2_b, fc3_w, fc3_b,
                                        (float*)d_out);
}

// Round 29
// 74.934 us; speedup vs baseline: 1.2360x; 1.0591x over previous
//
#include <hip/hip_runtime.h>
#include <hip/hip_bf16.h>

#define BATCH 256
#define L 1024
#define C 16
#define POOL 512
#define PCOLS 5632
#define FDIM 90112        // 11 levels * 8192
#define H1 128
#define H2 64

#define KS 256            // split-K factor for fc1 mfma GEMM
#define KCHUNK (FDIM / KS)   // 352

#define SROW 24                    // bf16 per state row (48B, 16B-aligned)
#define SBUF (1025 * SROW)         // +1 zero row
#define TREE_LDS_BYTES (2 * SBUF * 2 + 2047 * 4)   // bufs + node_w cache

typedef float f32x4 __attribute__((ext_vector_type(4)));
typedef short bf16x8 __attribute__((ext_vector_type(8)));
typedef unsigned long long u64;

__device__ __forceinline__ unsigned short f2b(float f) {
    union { __hip_bfloat16 h; unsigned short u; } cv;
    cv.h = __float2bfloat16(f);          // RNE, hardware v_cvt
    return cv.u;
}
__device__ __forceinline__ unsigned int pk(float lo, float hi) {
    return (unsigned int)f2b(lo) | ((unsigned int)f2b(hi) << 16);
}

// ---------------- Kernel 1: tree via MFMA (TRANSPOSED D), w1 permute interleaved ----
// mfma(window, weights) -> D[pos][co]: lane holds 4 consecutive POSITIONS (rows
// 4g+r) for ONE channel (n) -> pooling is in-register, no shfl, no divergence.
// pooled layout: f_new = level*8192 + pos2*16 + c   (w1 permuted to match).
__launch_bounds__(1024, 4)
__global__ void tree_kernel(const float* __restrict__ x,
                            const float* __restrict__ leaf_w,
                            const float* __restrict__ leaf_b,
                            const float* __restrict__ conv_w,
                            const float* __restrict__ conv_b,
                            const float* __restrict__ bn_gamma,
                            const float* __restrict__ bn_beta,
                            const float* __restrict__ node_w,
                            unsigned short* __restrict__ pooledb,
                            const float* __restrict__ w1,
                            unsigned short* __restrict__ w1p) {
    extern __shared__ short smem[];
    short* buf0 = smem;
    short* buf1 = smem + SBUF;
    float* nwl  = (float*)(smem + 2 * SBUF);   // node_w cache (2047 floats)

    const int b   = blockIdx.x;
    const int tid = threadIdx.x;
    const int lane = tid & 63;
    const int wv   = tid >> 6;
    const int n    = lane & 15;
    const int g    = lane >> 4;

    if (tid < SROW) {
        buf0[1024 * SROW + tid] = 0;
        buf1[1024 * SROW + tid] = 0;
    }
    for (int i = tid; i < 2047; i += 1024) nwl[i] = node_w[i];

    bf16x8 A1, A2;
#pragma unroll
    for (int j = 0; j < 8; ++j) {
        const int ci = (g & 1) * 8 + j;
        A1[j] = (short)f2b(conv_w[(n * C + ci) * 3 + (g >> 1)]);
        A2[j] = (g < 2) ? (short)f2b(conv_w[(n * C + ci) * 3 + 2]) : (short)0;
    }
    // per-lane epilogue constants for channel n (D is transposed now)
    const float scn = bn_gamma[n] / sqrtf(1.0f + 1e-5f);
    const float btn = conv_b[n] * scn + bn_beta[n];

    const int gbase = b * 11264 + tid;

    // ---- leaf stage: 1 position per thread ----
    {
        const float xv = x[b * L + tid];
        const float nw = node_w[tid];
        const float4* lwa = (const float4*)(leaf_w + 16 * tid);
        const float4* lba = (const float4*)(leaf_b + 16 * tid);
        short* row = buf0 + tid * SROW;
#pragma unroll 1
        for (int q = 0; q < 4; ++q) {
            float4 wq = lwa[q], bq = lba[q];
            float v0 = (xv * wq.x + bq.x) * nw;
            float v1 = (xv * wq.y + bq.y) * nw;
            float v2 = (xv * wq.z + bq.z) * nw;
            float v3 = (xv * wq.w + bq.w) * nw;
            *(u64*)(row + 4 * q) =
                (u64)pk(v0, v1) | ((u64)pk(v2, v3) << 32);
            float p0 = fmaxf(v0, __shfl_xor(v0, 1));
            float p1 = fmaxf(v1, __shfl_xor(v1, 1));
            float p2 = fmaxf(v2, __shfl_xor(v2, 1));
            float p3 = fmaxf(v3, __shfl_xor(v3, 1));
            if (!(tid & 1)) {
                *(u64*)(pooledb + (long)b * FDIM + (tid >> 1) * 16 + 4 * q) =
                    (u64)pk(p0, p1) | ((u64)pk(p2, p3) << 32);
            }
        }
        __syncthreads();   // zero rows + nwl + leaf state visible to all waves
    }

    // ---- 10 levels via MFMA, one permute round interleaved per level ----
    short* bin  = buf0;
    short* bout = buf1;
    int noff = L;
    for (int d = 0; d < 10; ++d) {
        const int sh = d + 1;
        const int mask = (1 << sh) - 1;

        // --- permute round d (VMEM latency hides under the level's LDS/MFMA) ---
        {
            const int gidx = gbase + d * 1024;
            const int pos2 = gidx & 511;
            const int c4   = (gidx >> 9) & 3;
            const int un   = gidx >> 11;          // 0..1407
            const int lev  = un >> 7;
            const int nr   = un & 127;
            const float* src = w1 + (long)nr * FDIM + lev * POOL + pos2;
            float f0 = src[(c4 * 4 + 0) * PCOLS];
            float f1 = src[(c4 * 4 + 1) * PCOLS];
            float f2 = src[(c4 * 4 + 2) * PCOLS];
            float f3 = src[(c4 * 4 + 3) * PCOLS];
            *(u64*)(w1p + (long)nr * FDIM + lev * 8192 + pos2 * 16 + c4 * 4) =
                (u64)pk(f0, f1) | ((u64)pk(f2, f3) << 32);
        }

        // --- tree level: phase 1, all tap reads ---
        bf16x8 B1s[4], B2s[4];
#pragma unroll
        for (int ti = 0; ti < 4; ++ti) {
            const int pos = (wv * 4 + ti) * 16 + n;
            const bool ok1 = (g >= 2) || ((pos & mask) != 0);
            const int r1 = ok1 ? (pos + (g >> 1) - 1) : 1024;
            B1s[ti] = *(const bf16x8*)(bin + r1 * SROW + (g & 1) * 8);
            const bool ok2 = ((pos & mask) != mask);
            const int r2 = ok2 ? (pos + 1) : 1024;
            B2s[ti] = *(const bf16x8*)(bin + r2 * SROW + (g & 1) * 8);
        }

        // --- phase 2: transposed MFMA + in-register pooling epilogue ---
#pragma unroll
        for (int ti = 0; ti < 4; ++ti) {
            const int base = (wv * 4 + ti) * 16 + 4 * g;   // lane's 4 positions

            f32x4 acc = {0.f, 0.f, 0.f, 0.f};
            acc = __builtin_amdgcn_mfma_f32_16x16x32_bf16(B1s[ti], A1, acc, 0, 0, 0);
            acc = __builtin_amdgcn_mfma_f32_16x16x32_bf16(B2s[ti], A2, acc, 0, 0, 0);

            float z[4];
#pragma unroll
            for (int r = 0; r < 4; ++r) {
                const float nwv = nwl[noff + ((base + r) >> sh)];
                z[r] = fmaxf(fmaf(scn, acc[r], btn), 0.f) * nwv;
            }

            if (d < 9) {
#pragma unroll
                for (int r = 0; r < 4; ++r)
                    bout[(base + r) * SROW + n] = (short)f2b(z[r]);
            }

            // pooling pairs are in-register now
            const int pos2 = base >> 1;
            unsigned short* pp = pooledb + (long)b * FDIM + sh * 8192 + pos2 * 16 + n;
            pp[0]  = f2b(fmaxf(z[0], z[1]));
            pp[16] = f2b(fmaxf(z[2], z[3]));
        }

        if (d >= 5 && d < 9) {
            __syncthreads();
        } else {
            asm volatile("s_waitcnt lgkmcnt(0)" ::: "memory");
        }

        short* t = bin; bin = bout; bout = t;
        noff += (512 >> d);
    }

    // --- final permute round (j = 10) ---
    {
        const int gidx = gbase + 10 * 1024;
        const int pos2 = gidx & 511;
        const int c4   = (gidx >> 9) & 3;
        const int un   = gidx >> 11;
        const int lev  = un >> 7;
        const int nr   = un & 127;
        const float* src = w1 + (long)nr * FDIM + lev * POOL + pos2;
        float f0 = src[(c4 * 4 + 0) * PCOLS];
        float f1 = src[(c4 * 4 + 1) * PCOLS];
        float f2 = src[(c4 * 4 + 2) * PCOLS];
        float f3 = src[(c4 * 4 + 3) * PCOLS];
        *(u64*)(w1p + (long)nr * FDIM + lev * 8192 + pos2 * 16 + c4 * 4) =
            (u64)pk(f0, f1) | ((u64)pk(f2, f3) << 32);
    }
}

// ---------------- Kernel 2: fc1 via MFMA, full 256x128/block, BF16 partials --------
__launch_bounds__(512, 2)
__global__ void fc1_mfma(const unsigned short* __restrict__ pooledb,
                         const unsigned short* __restrict__ w1b,
                         unsigned int* __restrict__ p32) {
    const int ks  = blockIdx.x;          // 0..255

    const int tid  = threadIdx.x;
    const int wv   = tid >> 6;           // 0..7
    const int lane = tid & 63;
    const int lrow = lane & 15;
    const int lk   = (lane >> 4) * 8;

    const int m0 = wv * 32;
    const int kb = ks * KCHUNK;

    const unsigned short* ap0 = pooledb + (long)(m0 + lrow) * FDIM + kb + lk;
    const unsigned short* ap1 = ap0 + (long)16 * FDIM;
    const unsigned short* bp  = w1b + (long)lrow * FDIM + kb + lk;

    f32x4 acc[2][8];
#pragma unroll
    for (int i = 0; i < 2; ++i)
#pragma unroll
        for (int ct = 0; ct < 8; ++ct) acc[i][ct] = (f32x4){0.f, 0.f, 0.f, 0.f};

#pragma unroll 1
    for (int kk = 0; kk < KCHUNK; kk += 32) {
        bf16x8 a0 = *(const bf16x8*)(ap0 + kk);
        bf16x8 a1 = *(const bf16x8*)(ap1 + kk);
#pragma unroll
        for (int ct = 0; ct < 8; ++ct) {
            bf16x8 bv = *(const bf16x8*)(bp + (long)(ct * 16) * FDIM + kk);
            acc[0][ct] = __builtin_amdgcn_mfma_f32_16x16x32_bf16(a0, bv, acc[0][ct], 0, 0, 0);
            acc[1][ct] = __builtin_amdgcn_mfma_f32_16x16x32_bf16(a1, bv, acc[1][ct], 0, 0, 0);
        }
    }

    // C/D: col = lane&15, row = (lane>>4)*4 + reg  [m89-verified]
    const int rbase = (lane >> 4) * 4;
    const int half  = lane & 1;          // 0 -> i=0 rows, 1 -> i=1 rows
    const int cpair = (lane & 15) >> 1;
#pragma unroll
    for (int r = 0; r < 4; ++r) {
        const int row = m0 + (half << 4) + rbase + r;
        unsigned int* p = p32 + (long)row * (KS * 64) + ks * 64 + cpair;
#pragma unroll
        for (int ct = 0; ct < 8; ++ct) {
            float x0 = acc[0][ct][r], x1 = acc[1][ct][r];
            float y0 = __shfl_xor(x0, 1), y1 = __shfl_xor(x1, 1);
            float lo = half ? y1 : x0;
            float hi = half ? x1 : y0;
            p[ct * 8] = pk(lo, hi);
        }
    }
}

// ---------------- Kernel 3: bf16 partial-reduce + fc1 bias/relu + fc2 + fc3 -------
__launch_bounds__(1024)
__global__ void fc_tail(const unsigned int* __restrict__ p32,
                        const float* __restrict__ fc1_b,
                        const float* __restrict__ w2,
                        const float* __restrict__ b2,
                        const float* __restrict__ w3,
                        const float* __restrict__ b3,
                        float* __restrict__ out) {
    __shared__ float red[16][H1];
    __shared__ float h1_s[H1];
    __shared__ float w2_s[H2 * 129];

    const int b = blockIdx.x;
    const int tid = threadIdx.x;
    const int t2 = tid & 63;      // col pair (cols 2*t2, 2*t2+1)
    const int q  = tid >> 6;      // ks group 0..15 (16 ks each)

    float s0 = 0.f, s1 = 0.f;
    const unsigned int* pb = p32 + (long)b * (KS * 64) + (q * 16) * 64 + t2;
#pragma unroll
    for (int kt = 0; kt < 16; ++kt) {
        unsigned int v = pb[kt * 64];
        union { unsigned int u; float f; } lo, hi;
        lo.u = v << 16;
        hi.u = v & 0xffff0000u;
        s0 += lo.f;
        s1 += hi.f;
    }
    red[q][2 * t2]     = s0;
    red[q][2 * t2 + 1] = s1;

    for (int i = tid; i < H2 * H1; i += 1024) {
        int j = i >> 7, k = i & 127;
        w2_s[j * 129 + k] = w2[i];
    }
    __syncthreads();

    if (tid < 128) {
        float ss = 0.f;
#pragma unroll
        for (int qq = 0; qq < 16; ++qq) ss += red[qq][tid];
        h1_s[tid] = fmaxf(ss + fc1_b[tid], 0.f);
    }
    __syncthreads();

    if (tid < 64) {
        float a2 = 0.f;
#pragma unroll 8
        for (int k = 0; k < H1; ++k) a2 = fmaf(h1_s[k], w2_s[tid * 129 + k], a2);
        float h2 = fmaxf(a2 + b2[tid], 0.f);
        float r = h2 * w3[tid];
#pragma unroll
        for (int off = 32; off > 0; off >>= 1) r += __shfl_down(r, off);
        if (tid == 0) out[b] = r + b3[0];
    }
}

extern "C" void kernel_launch(void* const* d_in, const int* in_sizes, int n_in,
                              void* d_out, int out_size, void* d_ws, size_t ws_size,
                              hipStream_t stream) {
    const float* x        = (const float*)d_in[0];
    const float* leaf_w   = (const float*)d_in[1];
    const float* leaf_b   = (const float*)d_in[2];
    const float* conv_w   = (const float*)d_in[3];
    const float* conv_b   = (const float*)d_in[4];
    const float* bn_gamma = (const float*)d_in[5];
    const float* bn_beta  = (const float*)d_in[6];
    const float* node_w   = (const float*)d_in[7];
    const float* fc1_w    = (const float*)d_in[8];
    const float* fc1_b    = (const float*)d_in[9];
    const float* fc2_w    = (const float*)d_in[10];
    const float* fc2_b    = (const float*)d_in[11];
    const float* fc3_w    = (const float*)d_in[12];
    const float* fc3_b    = (const float*)d_in[13];

    // ws: pooled bf16 (46.1MB) | w1p bf16 (23.1MB) | partial bf16 (16.8MB) = 86MB
    unsigned short* pooledb = (unsigned short*)d_ws;
    unsigned short* w1p     = pooledb + (long)BATCH * FDIM;
    unsigned int*   p32     = (unsigned int*)(w1p + (long)H1 * FDIM);

    (void)hipFuncSetAttribute((const void*)tree_kernel,
                        hipFuncAttributeMaxDynamicSharedMemorySize, TREE_LDS_BYTES);

    tree_kernel<<<BATCH, 1024, TREE_LDS_BYTES, stream>>>(
        x, leaf_w, leaf_b, conv_w, conv_b, bn_gamma, bn_beta, node_w, pooledb,
        fc1_w, w1p);

    fc1_mfma<<<KS, 512, 0, stream>>>(pooledb, w1p, p32);

    fc_tail<<<BATCH, 1024, 0, stream>>>(p32, fc1_b, fc2_w, fc2_b, fc3_w, fc3_b,
                                        (float*)d_out);
}